// Round 3
// baseline (232.870 us; speedup 1.0000x reference)
//
#include <hip/hip_runtime.h>
#include <hip/hip_bf16.h>

typedef float f32x4 __attribute__((ext_vector_type(4)));
typedef short bf16x8 __attribute__((ext_vector_type(8)));
typedef short s16x4 __attribute__((ext_vector_type(4)));
typedef unsigned int u32;

#define MFMA16(a, b, c) __builtin_amdgcn_mfma_f32_16x16x32_bf16((a), (b), (c), 0, 0, 0)

// round-to-nearest-even float -> bf16 bits
__device__ __forceinline__ unsigned short f2bf(float x) {
    union { float f; unsigned int u; } a; a.f = x;
    unsigned int r = a.u + 0x7fffu + ((a.u >> 16) & 1u);
    return (unsigned short)(r >> 16);
}

// ---------------------------------------------------------------------------
// prep: pack bf16 transposed weights + pre-gathered bias/mask tables into ws
//   WT  [c=384][kk=128] bf16, c = h*96 + p*32 + n   (p: 0=q,1=k,2=v)
//   WoT [f=128][e=128]  bf16  (WoT[f][e] = Wo[e][f])
//   bqkv[384] f32 (same c indexing)
//   bm  [v=4][qt=4][kt=4][lane=64][r=4] f32: (bias*log2e, -1e30 if masked)
//     for q = qt*16 + (lane&15), k = kt*16 + (lane>>4)*4 + r   (swapped layout)
// ---------------------------------------------------------------------------
__global__ void prep_kernel(const float* __restrict__ Wq, const float* __restrict__ bq,
                            const float* __restrict__ Wk, const float* __restrict__ bk,
                            const float* __restrict__ Wv, const float* __restrict__ bv,
                            const float* __restrict__ pos_bias, const float* __restrict__ Wo,
                            unsigned short* __restrict__ WT, unsigned short* __restrict__ WoT,
                            float* __restrict__ bqkv, float* __restrict__ bm) {
    const float LOG2E = 1.4426950408889634f;
    int t = blockIdx.x * blockDim.x + threadIdx.x;
    int nt = gridDim.x * blockDim.x;
    for (int i = t; i < 384 * 128; i += nt) {
        int c = i >> 7, kk = i & 127;
        int h = c / 96, rem = c - h * 96, p = rem >> 5, n = rem & 31;
        const float* W = (p == 0) ? Wq : (p == 1 ? Wk : Wv);
        WT[i] = f2bf(W[(h * 128 + kk) * 32 + n]);
    }
    for (int i = t; i < 128 * 128; i += nt) {
        int n = i >> 7, kk = i & 127;
        WoT[i] = f2bf(Wo[kk * 128 + n]);
    }
    for (int i = t; i < 384; i += nt) {
        int h = i / 96, rem = i - h * 96, p = rem >> 5, n = rem & 31;
        const float* b = (p == 0) ? bq : (p == 1 ? bk : bv);
        bqkv[i] = b[h * 32 + n];
    }
    for (int i = t; i < 4 * 4 * 4 * 64 * 4; i += nt) {
        int r = i & 3, l = (i >> 2) & 63, kt = (i >> 8) & 3, qt = (i >> 10) & 3, v = (i >> 12) & 3;
        int q = qt * 16 + (l & 15);
        int k = kt * 16 + ((l >> 4) << 2) + r;
        int qi = q >> 3, qj = q & 7, ki = k >> 3, kj = k & 7;
        bool masked = (((v >> 1) != 0) && ((qi < 4) != (ki < 4))) ||
                      (((v & 1) != 0) && ((qj < 4) != (kj < 4)));
        bm[i] = masked ? -1e30f : pos_bias[(qi - ki + 7) * 15 + (qj - kj + 7)] * LOG2E;
    }
}

// ---------------------------------------------------------------------------
// fused Swin window attention v3: persistent blocks (grid=768, 3/CU), each
// block grid-strides over windows with a one-window-ahead register prefetch
// of X (T14): the only HBM read is issued under the previous window's
// compute. Stage5 (output proj) of window i runs at the top of iteration i+1
// so its stores overlap compute. 3 barriers/window.
// LDS (48 KB, shorts):
//   R1 [0,8192)      : xb[64][128]  <-> V^T[4 heads][32][64] overlay
//   R2 [8192,24576)  : QK[4 heads][64][64]; attnout[64][128] overlays h=0,1
// QK / V^T are wave-private (wave h = head h) -> no barrier between
// projection-write and QK^T/PV-read (in-wave lgkmcnt ordering suffices).
// ---------------------------------------------------------------------------
#define SWIN_GRID 768

__launch_bounds__(256, 3)
__global__ void swin_kernel(const float* __restrict__ patches,
                            const unsigned short* __restrict__ WT,
                            const float* __restrict__ bqkv,
                            const float* __restrict__ bm,
                            const unsigned short* __restrict__ WoT,
                            const float* __restrict__ bo,
                            float* __restrict__ out) {
    __shared__ short lds[24576];
    const int tid = threadIdx.x;
    const int lane = tid & 63;
    const int h = tid >> 6;
    const int l15 = lane & 15, l4 = lane >> 4;
    const int sw15 = (l15 & 7) << 3;  // swizzle for rows indexed by l15
    const f32x4 zero = {0.f, 0.f, 0.f, 0.f};

    const int qkbase = 8192 + h * 4096;  // QK[h][64 tok][64 cc]
    const int vbase = h * 2048;          // V^T[h][32 n][64 tok]
    const int sA = ((l4 & 1) << 5) + l15;  // P-exchange src lane, words 0,1
    const int sB = sA + 16;                //                     words 2,3
    const float rs2 = 0.2550348660629988f;  // log2(e)/sqrt(32)
    const float4* bmv = reinterpret_cast<const float4*>(bm);

    int w = blockIdx.x;
    float4 px[8];
    // ---- prologue: load + stage X(w) ----
    {
        const float4* src = reinterpret_cast<const float4*>(patches + (size_t)w * 8192);
        #pragma unroll
        for (int i = 0; i < 8; ++i) px[i] = src[i * 256 + tid];
    }
    #pragma unroll
    for (int i = 0; i < 8; ++i) {
        int idx4 = i * 256 + tid;
        int row = idx4 >> 5, col = (idx4 & 31) << 2;
        s16x4 pk;
        pk[0] = (short)f2bf(px[i].x); pk[1] = (short)f2bf(px[i].y);
        pk[2] = (short)f2bf(px[i].z); pk[3] = (short)f2bf(px[i].w);
        *reinterpret_cast<s16x4*>(&lds[row * 128 + (col ^ ((row & 7) << 3))]) = pk;
    }
    __syncthreads();  // B_e0: xb(first) ready

    int prev = -1;
    for (; w < 4096; w += SWIN_GRID) {
        // ---- stage5 for PREVIOUS window (reads attnout in R2, stores out) ----
        if (prev >= 0) {
            bf16x8 wf[2][4];
            #pragma unroll
            for (int nt = 0; nt < 2; ++nt)
                #pragma unroll
                for (int ks = 0; ks < 4; ++ks)
                    wf[nt][ks] = *reinterpret_cast<const bf16x8*>(
                        &WoT[(h * 32 + nt * 16 + l15) * 128 + ks * 32 + l4 * 8]);
            float4 bo4[2];
            #pragma unroll
            for (int nt = 0; nt < 2; ++nt)
                bo4[nt] = *reinterpret_cast<const float4*>(&bo[h * 32 + nt * 16 + l4 * 4]);
            float* outw = out + (size_t)prev * 8192;
            #pragma unroll
            for (int mt = 0; mt < 4; ++mt) {
                bf16x8 af[4];
                #pragma unroll
                for (int ks = 0; ks < 4; ++ks)
                    af[ks] = *reinterpret_cast<const bf16x8*>(
                        &lds[8192 + (mt * 16 + l15) * 128 + ((ks * 32 + l4 * 8) ^ sw15)]);
                __builtin_amdgcn_s_setprio(1);
                #pragma unroll
                for (int nt = 0; nt < 2; ++nt) {
                    f32x4 a = zero;
                    #pragma unroll
                    for (int ks = 0; ks < 4; ++ks) a = MFMA16(wf[nt][ks], af[ks], a);
                    float4 st;
                    st.x = a[0] + bo4[nt].x;
                    st.y = a[1] + bo4[nt].y;
                    st.z = a[2] + bo4[nt].z;
                    st.w = a[3] + bo4[nt].w;
                    *reinterpret_cast<float4*>(
                        &outw[(size_t)(mt * 16 + l15) * 128 + h * 32 + nt * 16 + l4 * 4]) = st;
                }
                __builtin_amdgcn_s_setprio(0);
            }
        }

        // ---- xa fragment reads (xb in R1) ----
        bf16x8 xa[4][4];
        #pragma unroll
        for (int mt = 0; mt < 4; ++mt)
            #pragma unroll
            for (int ks = 0; ks < 4; ++ks)
                xa[mt][ks] = *reinterpret_cast<const bf16x8*>(
                    &lds[(mt * 16 + l15) * 128 + ((ks * 32 + l4 * 8) ^ sw15)]);
        __syncthreads();  // B_b: R1 xa reads + R2 attnout reads done

        // ---- prefetch X(next window) into registers (in flight under compute)
        {
            int wn = w + SWIN_GRID;
            const float4* srcn = reinterpret_cast<const float4*>(
                patches + (size_t)(wn < 4096 ? wn : w) * 8192);
            #pragma unroll
            for (int i = 0; i < 8; ++i) px[i] = srcn[i * 256 + tid];
        }

        // ---- stage2b: Q,K projection (SWAPPED mfma(W,X)) -> QK[h], b64 writes
        #pragma unroll
        for (int ct = 0; ct < 4; ++ct) {
            bf16x8 wb[4];
            #pragma unroll
            for (int ks = 0; ks < 4; ++ks)
                wb[ks] = *reinterpret_cast<const bf16x8*>(
                    &WT[(h * 96 + ct * 16 + l15) * 128 + ks * 32 + l4 * 8]);
            float b4[4];
            #pragma unroll
            for (int r = 0; r < 4; ++r) b4[r] = bqkv[h * 96 + ct * 16 + l4 * 4 + r];
            __builtin_amdgcn_s_setprio(1);
            #pragma unroll
            for (int mt = 0; mt < 4; ++mt) {
                f32x4 a = zero;
                #pragma unroll
                for (int ks = 0; ks < 4; ++ks) a = MFMA16(wb[ks], xa[mt][ks], a);
                int tok = mt * 16 + l15;
                int cc0 = (ct * 16 + l4 * 4) ^ sw15;  // tok&7 == l15&7
                s16x4 pk;
                #pragma unroll
                for (int r = 0; r < 4; ++r) pk[r] = (short)f2bf(a[r] + b4[r]);
                *reinterpret_cast<s16x4*>(&lds[qkbase + tok * 64 + cc0]) = pk;
            }
            __builtin_amdgcn_s_setprio(0);
        }

        // ---- stage2c: V projection (normal mfma(X,W)) -> V^T[h], b64 writes
        #pragma unroll
        for (int ctv = 0; ctv < 2; ++ctv) {
            bf16x8 wb[4];
            #pragma unroll
            for (int ks = 0; ks < 4; ++ks)
                wb[ks] = *reinterpret_cast<const bf16x8*>(
                    &WT[(h * 96 + 64 + ctv * 16 + l15) * 128 + ks * 32 + l4 * 8]);
            float bb = bqkv[h * 96 + 64 + ctv * 16 + l15];
            __builtin_amdgcn_s_setprio(1);
            #pragma unroll
            for (int mt = 0; mt < 4; ++mt) {
                f32x4 a = zero;
                #pragma unroll
                for (int ks = 0; ks < 4; ++ks) a = MFMA16(xa[mt][ks], wb[ks], a);
                int n = ctv * 16 + l15;
                int tok0 = (mt * 16 + l4 * 4) ^ sw15;  // n&7 == l15&7
                s16x4 pk;
                #pragma unroll
                for (int r = 0; r < 4; ++r) pk[r] = (short)f2bf(a[r] + bb);
                *reinterpret_cast<s16x4*>(&lds[vbase + n * 64 + tok0]) = pk;
            }
            __builtin_amdgcn_s_setprio(0);
        }

        // ---- stage3+4 (wave-local): swapped QK^T, in-reg softmax, shfl P,
        //      swapped PV. QK/V^T are wave-private -> no barrier needed. ----
        bf16x8 kfrag[4], vf[2][2];
        #pragma unroll
        for (int kt = 0; kt < 4; ++kt)
            kfrag[kt] = *reinterpret_cast<const bf16x8*>(
                &lds[qkbase + (kt * 16 + l15) * 64 + ((32 + l4 * 8) ^ sw15)]);
        #pragma unroll
        for (int nt = 0; nt < 2; ++nt)
            #pragma unroll
            for (int ks = 0; ks < 2; ++ks)
                vf[nt][ks] = *reinterpret_cast<const bf16x8*>(
                    &lds[vbase + (nt * 16 + l15) * 64 + ((ks * 32 + l4 * 8) ^ sw15)]);

        f32x4 O[2][4];  // [nt][qt], O^T layout: row n, col q
        #pragma unroll
        for (int nt = 0; nt < 2; ++nt)
            #pragma unroll
            for (int qt = 0; qt < 4; ++qt) O[nt][qt] = zero;

        const int mv = (((w >> 4) & 15) == 15 ? 2 : 0) + ((w & 15) == 15 ? 1 : 0);

        #pragma unroll
        for (int qt = 0; qt < 4; ++qt) {
            bf16x8 qfrag = *reinterpret_cast<const bf16x8*>(
                &lds[qkbase + (qt * 16 + l15) * 64 + ((l4 * 8) ^ sw15)]);
            f32x4 LT[4];
            __builtin_amdgcn_s_setprio(1);
            #pragma unroll
            for (int kt = 0; kt < 4; ++kt) LT[kt] = MFMA16(kfrag[kt], qfrag, zero);
            __builtin_amdgcn_s_setprio(0);

            // lane holds S[q=qt*16+l15][k=kt*16+l4*4+r]
            float x[4][4];
            float m = -3.0e38f;
            #pragma unroll
            for (int kt = 0; kt < 4; ++kt) {
                float4 b4 = bmv[((mv * 4 + qt) * 4 + kt) * 64 + lane];
                x[kt][0] = LT[kt][0] * rs2 + b4.x;
                x[kt][1] = LT[kt][1] * rs2 + b4.y;
                x[kt][2] = LT[kt][2] * rs2 + b4.z;
                x[kt][3] = LT[kt][3] * rs2 + b4.w;
                m = fmaxf(m, fmaxf(fmaxf(x[kt][0], x[kt][1]), fmaxf(x[kt][2], x[kt][3])));
            }
            m = fmaxf(m, __shfl_xor(m, 16));
            m = fmaxf(m, __shfl_xor(m, 32));
            float s = 0.f;
            #pragma unroll
            for (int kt = 0; kt < 4; ++kt)
                #pragma unroll
                for (int r = 0; r < 4; ++r) {
                    float e = exp2f(x[kt][r] - m);
                    x[kt][r] = e;
                    s += e;
                }
            s += __shfl_xor(s, 16);
            s += __shfl_xor(s, 32);
            float inv = 1.0f / s;

            u32 wp[4][2];
            #pragma unroll
            for (int kt = 0; kt < 4; ++kt) {
                wp[kt][0] = (u32)f2bf(x[kt][0] * inv) | ((u32)f2bf(x[kt][1] * inv) << 16);
                wp[kt][1] = (u32)f2bf(x[kt][2] * inv) | ((u32)f2bf(x[kt][3] * inv) << 16);
            }
            // exchange -> B-frag of PV: lane needs P[q=l15][k=ks*32+l4*8+j]
            u32 fr[2][4];
            #pragma unroll
            for (int kt = 0; kt < 4; ++kt) {
                u32 a0 = __shfl(wp[kt][0], sA);
                u32 a1 = __shfl(wp[kt][1], sA);
                u32 b0 = __shfl(wp[kt][0], sB);
                u32 b1 = __shfl(wp[kt][1], sB);
                if ((kt & 1) == (l4 >> 1)) {
                    const int ks = kt >> 1;
                    fr[ks][0] = a0; fr[ks][1] = a1; fr[ks][2] = b0; fr[ks][3] = b1;
                }
            }
            bf16x8 pf0, pf1;
            {
                union { u32 u[4]; bf16x8 v; } c0, c1;
                c0.u[0] = fr[0][0]; c0.u[1] = fr[0][1]; c0.u[2] = fr[0][2]; c0.u[3] = fr[0][3];
                c1.u[0] = fr[1][0]; c1.u[1] = fr[1][1]; c1.u[2] = fr[1][2]; c1.u[3] = fr[1][3];
                pf0 = c0.v; pf1 = c1.v;
            }
            __builtin_amdgcn_s_setprio(1);
            #pragma unroll
            for (int nt = 0; nt < 2; ++nt) {
                O[nt][qt] = MFMA16(vf[nt][0], pf0, O[nt][qt]);
                O[nt][qt] = MFMA16(vf[nt][1], pf1, O[nt][qt]);
            }
            __builtin_amdgcn_s_setprio(0);
        }
        __syncthreads();  // B_d: all R1 (V^T) + R2 (QK) reads done

        // ---- stage X(next) -> xb (R1) + attnout -> R2, both b64 writes ----
        #pragma unroll
        for (int i = 0; i < 8; ++i) {
            int idx4 = i * 256 + tid;
            int row = idx4 >> 5, col = (idx4 & 31) << 2;
            s16x4 pk;
            pk[0] = (short)f2bf(px[i].x); pk[1] = (short)f2bf(px[i].y);
            pk[2] = (short)f2bf(px[i].z); pk[3] = (short)f2bf(px[i].w);
            *reinterpret_cast<s16x4*>(&lds[row * 128 + (col ^ ((row & 7) << 3))]) = pk;
        }
        #pragma unroll
        for (int nt = 0; nt < 2; ++nt)
            #pragma unroll
            for (int qt = 0; qt < 4; ++qt) {
                int q = qt * 16 + l15;
                int f0 = (h * 32 + nt * 16 + l4 * 4) ^ sw15;  // q&7 == l15&7
                s16x4 pk;
                #pragma unroll
                for (int r = 0; r < 4; ++r) pk[r] = (short)f2bf(O[nt][qt][r]);
                *reinterpret_cast<s16x4*>(&lds[8192 + q * 128 + f0]) = pk;
            }
        prev = w;
        __syncthreads();  // B_e: xb(next) + attnout published
    }

    // ---- epilogue: stage5 for the last window ----
    {
        bf16x8 wf[2][4];
        #pragma unroll
        for (int nt = 0; nt < 2; ++nt)
            #pragma unroll
            for (int ks = 0; ks < 4; ++ks)
                wf[nt][ks] = *reinterpret_cast<const bf16x8*>(
                    &WoT[(h * 32 + nt * 16 + l15) * 128 + ks * 32 + l4 * 8]);
        float4 bo4[2];
        #pragma unroll
        for (int nt = 0; nt < 2; ++nt)
            bo4[nt] = *reinterpret_cast<const float4*>(&bo[h * 32 + nt * 16 + l4 * 4]);
        float* outw = out + (size_t)prev * 8192;
        #pragma unroll
        for (int mt = 0; mt < 4; ++mt) {
            bf16x8 af[4];
            #pragma unroll
            for (int ks = 0; ks < 4; ++ks)
                af[ks] = *reinterpret_cast<const bf16x8*>(
                    &lds[8192 + (mt * 16 + l15) * 128 + ((ks * 32 + l4 * 8) ^ sw15)]);
            #pragma unroll
            for (int nt = 0; nt < 2; ++nt) {
                f32x4 a = zero;
                #pragma unroll
                for (int ks = 0; ks < 4; ++ks) a = MFMA16(wf[nt][ks], af[ks], a);
                float4 st;
                st.x = a[0] + bo4[nt].x;
                st.y = a[1] + bo4[nt].y;
                st.z = a[2] + bo4[nt].z;
                st.w = a[3] + bo4[nt].w;
                *reinterpret_cast<float4*>(
                    &outw[(size_t)(mt * 16 + l15) * 128 + h * 32 + nt * 16 + l4 * 4]) = st;
            }
        }
    }
}

extern "C" void kernel_launch(void* const* d_in, const int* in_sizes, int n_in,
                              void* d_out, int out_size, void* d_ws, size_t ws_size,
                              hipStream_t stream) {
    const float* patches  = (const float*)d_in[0];
    const float* Wq       = (const float*)d_in[1];
    const float* bq       = (const float*)d_in[2];
    const float* Wk       = (const float*)d_in[3];
    const float* bk       = (const float*)d_in[4];
    const float* Wv       = (const float*)d_in[5];
    const float* bv       = (const float*)d_in[6];
    const float* pos_bias = (const float*)d_in[7];
    const float* Wo       = (const float*)d_in[8];
    const float* bo       = (const float*)d_in[9];
    // d_in[10] (mask) is recomputed analytically in prep_kernel.

    char* ws = (char*)d_ws;
    unsigned short* WT  = (unsigned short*)(ws);            // 98304 B
    unsigned short* WoT = (unsigned short*)(ws + 98304);    // 32768 B
    float* bqkv         = (float*)(ws + 131072);            // 1536 B
    float* bm           = (float*)(ws + 132608);            // 65536 B (16B-aligned)

    hipLaunchKernelGGL(prep_kernel, dim3(64), dim3(256), 0, stream,
                       Wq, bq, Wk, bk, Wv, bv, pos_bias, Wo, WT, WoT, bqkv, bm);
    hipLaunchKernelGGL(swin_kernel, dim3(SWIN_GRID), dim3(256), 0, stream,
                       patches, WT, bqkv, bm, WoT, bo, (float*)d_out);
}

// Round 4
// 133.354 us; speedup vs baseline: 1.7463x; 1.7463x over previous
//
#include <hip/hip_runtime.h>
#include <hip/hip_bf16.h>

typedef float f32x4 __attribute__((ext_vector_type(4)));
typedef short bf16x8 __attribute__((ext_vector_type(8)));
typedef short s16x4 __attribute__((ext_vector_type(4)));
typedef unsigned int u32;

#define MFMA16(a, b, c) __builtin_amdgcn_mfma_f32_16x16x32_bf16((a), (b), (c), 0, 0, 0)

// pack two floats -> u32 of 2 bf16 (RNE, v_cvt_pk_bf16_f32)
__device__ __forceinline__ u32 pk2(float lo, float hi) {
    union { __hip_bfloat162 h; u32 u; } c;
    c.h = __float22bfloat162_rn(float2{lo, hi});
    return c.u;
}

// round-to-nearest-even float -> bf16 bits (host-independent helper for prep)
__device__ __forceinline__ unsigned short f2bf(float x) {
    union { float f; unsigned int u; } a; a.f = x;
    unsigned int r = a.u + 0x7fffu + ((a.u >> 16) & 1u);
    return (unsigned short)(r >> 16);
}

// ---------------------------------------------------------------------------
// prep: pack bf16 transposed weights + pre-gathered bias/mask tables into ws
//   WT  [c=384][kk=128] bf16, c = h*96 + p*32 + n   (p: 0=q,1=k,2=v)
//   WoT [f=128][e=128]  bf16  (WoT[f][e] = Wo[e][f])
//   bqkv[384] f32 (same c indexing)
//   bm  [v=4][qt=4][kt=4][lane=64][r=4] f32: (bias*log2e, -1e30 if masked)
//     for q = qt*16 + (lane&15), k = kt*16 + (lane>>4)*4 + r   (swapped layout)
// ---------------------------------------------------------------------------
__global__ void prep_kernel(const float* __restrict__ Wq, const float* __restrict__ bq,
                            const float* __restrict__ Wk, const float* __restrict__ bk,
                            const float* __restrict__ Wv, const float* __restrict__ bv,
                            const float* __restrict__ pos_bias, const float* __restrict__ Wo,
                            unsigned short* __restrict__ WT, unsigned short* __restrict__ WoT,
                            float* __restrict__ bqkv, float* __restrict__ bm) {
    const float LOG2E = 1.4426950408889634f;
    int t = blockIdx.x * blockDim.x + threadIdx.x;
    int nt = gridDim.x * blockDim.x;
    for (int i = t; i < 384 * 128; i += nt) {
        int c = i >> 7, kk = i & 127;
        int h = c / 96, rem = c - h * 96, p = rem >> 5, n = rem & 31;
        const float* W = (p == 0) ? Wq : (p == 1 ? Wk : Wv);
        WT[i] = f2bf(W[(h * 128 + kk) * 32 + n]);
    }
    for (int i = t; i < 128 * 128; i += nt) {
        int n = i >> 7, kk = i & 127;
        WoT[i] = f2bf(Wo[kk * 128 + n]);
    }
    for (int i = t; i < 384; i += nt) {
        int h = i / 96, rem = i - h * 96, p = rem >> 5, n = rem & 31;
        const float* b = (p == 0) ? bq : (p == 1 ? bk : bv);
        bqkv[i] = b[h * 32 + n];
    }
    for (int i = t; i < 4 * 4 * 4 * 64 * 4; i += nt) {
        int r = i & 3, l = (i >> 2) & 63, kt = (i >> 8) & 3, qt = (i >> 10) & 3, v = (i >> 12) & 3;
        int q = qt * 16 + (l & 15);
        int k = kt * 16 + ((l >> 4) << 2) + r;
        int qi = q >> 3, qj = q & 7, ki = k >> 3, kj = k & 7;
        bool masked = (((v >> 1) != 0) && ((qi < 4) != (ki < 4))) ||
                      (((v & 1) != 0) && ((qj < 4) != (kj < 4)));
        bm[i] = masked ? -1e30f : pos_bias[(qi - ki + 7) * 15 + (qj - kj + 7)] * LOG2E;
    }
}

// ---------------------------------------------------------------------------
// fused Swin window attention v4: one block (4 waves) per window, wave = head.
// Q and K never touch LDS: projection C-outputs are shfl-exchanged directly
// into QK^T fragments (same sA/sB pattern as the verified PV P-exchange).
// LDS (32 KB, shorts):
//   R1 [0,8192)      : xb[64][128]  -> V^T[4 heads][32][64] overlay (after B2)
//   R2 [8192,16384)  : attnout[64][128]
// 3 barriers/window; __launch_bounds__(256,4) -> 4 blocks/CU.
// ---------------------------------------------------------------------------
__launch_bounds__(256, 4)
__global__ void swin_kernel(const float* __restrict__ patches,
                            const unsigned short* __restrict__ WT,
                            const float* __restrict__ bqkv,
                            const float* __restrict__ bm,
                            const unsigned short* __restrict__ WoT,
                            const float* __restrict__ bo,
                            float* __restrict__ out) {
    __shared__ short lds[16384];
    const int win = blockIdx.x;
    const int tid = threadIdx.x;
    const int lane = tid & 63;
    const int h = tid >> 6;
    const int l15 = lane & 15, l4 = lane >> 4;
    const int sw15 = (l15 & 7) << 3;       // swizzle for rows congruent to l15 (mod 8)
    const f32x4 zero = {0.f, 0.f, 0.f, 0.f};
    const int sA = ((l4 & 1) << 5) + l15;  // exchange src lane, words 0,1
    const int sB = sA + 16;                //                    words 2,3
    const float rs2 = 0.2550348660629988f; // log2(e)/sqrt(32)
    const float4* bmv = reinterpret_cast<const float4*>(bm);

    // ---- stage 1: patches (f32) -> xb (bf16, swizzled) ----
    {
        const float4* src = reinterpret_cast<const float4*>(patches + (size_t)win * 8192);
        #pragma unroll
        for (int i = 0; i < 8; ++i) {
            int idx4 = i * 256 + tid;
            float4 v = src[idx4];
            int row = idx4 >> 5, col = (idx4 & 31) << 2;
            union { u32 u[2]; s16x4 s; } pk;
            pk.u[0] = pk2(v.x, v.y);
            pk.u[1] = pk2(v.z, v.w);
            *reinterpret_cast<s16x4*>(&lds[row * 128 + (col ^ ((row & 7) << 3))]) = pk.s;
        }
    }
    __syncthreads();  // B1: xb ready

    // ---- stage 2a: x fragments (all waves read all of xb) ----
    bf16x8 xa[4][4];
    #pragma unroll
    for (int mt = 0; mt < 4; ++mt)
        #pragma unroll
        for (int ks = 0; ks < 4; ++ks)
            xa[mt][ks] = *reinterpret_cast<const bf16x8*>(
                &lds[(mt * 16 + l15) * 128 + ((ks * 32 + l4 * 8) ^ sw15)]);
    __syncthreads();  // B2: xa reads done -> V^T may overlay xb

    // ---- stage 2b: Q,K projection (SWAPPED mfma(W,X)); C-out -> shfl-exchange
    //      directly into QK^T fragments (no LDS). ct 0,1 = Q; ct 2,3 = K. ----
    bf16x8 qf[4], kf[4];
    #pragma unroll
    for (int ct = 0; ct < 4; ++ct) {
        bf16x8 wb[4];
        #pragma unroll
        for (int ks = 0; ks < 4; ++ks)
            wb[ks] = *reinterpret_cast<const bf16x8*>(
                &WT[(h * 96 + ct * 16 + l15) * 128 + ks * 32 + l4 * 8]);
        float b4[4];
        #pragma unroll
        for (int r = 0; r < 4; ++r) b4[r] = bqkv[h * 96 + ct * 16 + l4 * 4 + r];
        #pragma unroll
        for (int mt = 0; mt < 4; ++mt) {
            f32x4 a = zero;
            __builtin_amdgcn_s_setprio(1);
            #pragma unroll
            for (int ks = 0; ks < 4; ++ks) a = MFMA16(wb[ks], xa[mt][ks], a);
            __builtin_amdgcn_s_setprio(0);
            u32 pw0 = pk2(a[0] + b4[0], a[1] + b4[1]);
            u32 pw1 = pk2(a[2] + b4[2], a[3] + b4[3]);
            u32 e0 = __shfl(pw0, sA);
            u32 e1 = __shfl(pw1, sA);
            u32 e2 = __shfl(pw0, sB);
            u32 e3 = __shfl(pw1, sB);
            if ((ct & 1) == (l4 >> 1)) {  // this lane's fragment comes from this ct
                union { u32 u[4]; bf16x8 v; } c;
                c.u[0] = e0; c.u[1] = e1; c.u[2] = e2; c.u[3] = e3;
                if (ct < 2) qf[mt] = c.v; else kf[mt] = c.v;
            }
        }
    }

    // ---- stage 2c: V projection (normal mfma(X,W)) -> V^T in R1, b64 writes
    #pragma unroll
    for (int ctv = 0; ctv < 2; ++ctv) {
        bf16x8 wb[4];
        #pragma unroll
        for (int ks = 0; ks < 4; ++ks)
            wb[ks] = *reinterpret_cast<const bf16x8*>(
                &WT[(h * 96 + 64 + ctv * 16 + l15) * 128 + ks * 32 + l4 * 8]);
        float bb = bqkv[h * 96 + 64 + ctv * 16 + l15];
        __builtin_amdgcn_s_setprio(1);
        #pragma unroll
        for (int mt = 0; mt < 4; ++mt) {
            f32x4 a = zero;
            #pragma unroll
            for (int ks = 0; ks < 4; ++ks) a = MFMA16(xa[mt][ks], wb[ks], a);
            int n = ctv * 16 + l15;
            int tok0 = (mt * 16 + l4 * 4) ^ sw15;  // n&7 == l15&7
            union { u32 u[2]; s16x4 s; } pk;
            pk.u[0] = pk2(a[0] + bb, a[1] + bb);
            pk.u[1] = pk2(a[2] + bb, a[3] + bb);
            *reinterpret_cast<s16x4*>(&lds[h * 2048 + n * 64 + tok0]) = pk.s;
        }
        __builtin_amdgcn_s_setprio(0);
    }

    // ---- stage 3+4 (wave-local, barrier-free): swapped QK^T, in-reg softmax,
    //      shfl-built P fragments, swapped PV ----
    bf16x8 vf[2][2];
    #pragma unroll
    for (int nt = 0; nt < 2; ++nt)
        #pragma unroll
        for (int ks = 0; ks < 2; ++ks)
            vf[nt][ks] = *reinterpret_cast<const bf16x8*>(
                &lds[h * 2048 + (nt * 16 + l15) * 64 + ((ks * 32 + l4 * 8) ^ sw15)]);

    f32x4 O[2][4];  // [nt][qt], O^T layout: row n, col q
    #pragma unroll
    for (int nt = 0; nt < 2; ++nt)
        #pragma unroll
        for (int qt = 0; qt < 4; ++qt) O[nt][qt] = zero;

    const int mv = (((win >> 4) & 15) == 15 ? 2 : 0) + ((win & 15) == 15 ? 1 : 0);

    float4 bcur[4], bnxt[4];
    #pragma unroll
    for (int kt = 0; kt < 4; ++kt) bcur[kt] = bmv[((mv * 4 + 0) * 4 + kt) * 64 + lane];

    #pragma unroll
    for (int qt = 0; qt < 4; ++qt) {
        f32x4 LT[4];
        __builtin_amdgcn_s_setprio(1);
        #pragma unroll
        for (int kt = 0; kt < 4; ++kt) LT[kt] = MFMA16(kf[kt], qf[qt], zero);
        __builtin_amdgcn_s_setprio(0);

        if (qt < 3) {  // prefetch next qt's bias/mask under this qt's softmax
            #pragma unroll
            for (int kt = 0; kt < 4; ++kt)
                bnxt[kt] = bmv[((mv * 4 + qt + 1) * 4 + kt) * 64 + lane];
        }

        // lane holds S[q=qt*16+l15][k=kt*16+l4*4+r]
        float x[4][4];
        float m = -3.0e38f;
        #pragma unroll
        for (int kt = 0; kt < 4; ++kt) {
            x[kt][0] = LT[kt][0] * rs2 + bcur[kt].x;
            x[kt][1] = LT[kt][1] * rs2 + bcur[kt].y;
            x[kt][2] = LT[kt][2] * rs2 + bcur[kt].z;
            x[kt][3] = LT[kt][3] * rs2 + bcur[kt].w;
            m = fmaxf(m, fmaxf(fmaxf(x[kt][0], x[kt][1]), fmaxf(x[kt][2], x[kt][3])));
        }
        m = fmaxf(m, __shfl_xor(m, 16));
        m = fmaxf(m, __shfl_xor(m, 32));
        float s = 0.f;
        #pragma unroll
        for (int kt = 0; kt < 4; ++kt)
            #pragma unroll
            for (int r = 0; r < 4; ++r) {
                float e = exp2f(x[kt][r] - m);
                x[kt][r] = e;
                s += e;
            }
        s += __shfl_xor(s, 16);
        s += __shfl_xor(s, 32);
        float inv = 1.0f / s;

        u32 wp[4][2];
        #pragma unroll
        for (int kt = 0; kt < 4; ++kt) {
            wp[kt][0] = pk2(x[kt][0] * inv, x[kt][1] * inv);
            wp[kt][1] = pk2(x[kt][2] * inv, x[kt][3] * inv);
        }
        // exchange -> B-frag of PV: lane needs P[q=l15][k=ks*32+l4*8+j]
        u32 fr[2][4];
        #pragma unroll
        for (int kt = 0; kt < 4; ++kt) {
            u32 a0 = __shfl(wp[kt][0], sA);
            u32 a1 = __shfl(wp[kt][1], sA);
            u32 b0 = __shfl(wp[kt][0], sB);
            u32 b1 = __shfl(wp[kt][1], sB);
            if ((kt & 1) == (l4 >> 1)) {
                const int ks = kt >> 1;
                fr[ks][0] = a0; fr[ks][1] = a1; fr[ks][2] = b0; fr[ks][3] = b1;
            }
        }
        bf16x8 pf0, pf1;
        {
            union { u32 u[4]; bf16x8 v; } c0, c1;
            c0.u[0] = fr[0][0]; c0.u[1] = fr[0][1]; c0.u[2] = fr[0][2]; c0.u[3] = fr[0][3];
            c1.u[0] = fr[1][0]; c1.u[1] = fr[1][1]; c1.u[2] = fr[1][2]; c1.u[3] = fr[1][3];
            pf0 = c0.v; pf1 = c1.v;
        }
        __builtin_amdgcn_s_setprio(1);
        #pragma unroll
        for (int nt = 0; nt < 2; ++nt) {
            O[nt][qt] = MFMA16(vf[nt][0], pf0, O[nt][qt]);
            O[nt][qt] = MFMA16(vf[nt][1], pf1, O[nt][qt]);
        }
        __builtin_amdgcn_s_setprio(0);

        if (qt < 3) {
            #pragma unroll
            for (int kt = 0; kt < 4; ++kt) bcur[kt] = bnxt[kt];
        }
    }

    // ---- stage 5 weight loads issued early (hide under attnout + barrier) ----
    bf16x8 wf[2][4];
    #pragma unroll
    for (int nt = 0; nt < 2; ++nt)
        #pragma unroll
        for (int ks = 0; ks < 4; ++ks)
            wf[nt][ks] = *reinterpret_cast<const bf16x8*>(
                &WoT[(h * 32 + nt * 16 + l15) * 128 + ks * 32 + l4 * 8]);
    float4 bo4[2];
    #pragma unroll
    for (int nt = 0; nt < 2; ++nt)
        bo4[nt] = *reinterpret_cast<const float4*>(&bo[h * 32 + nt * 16 + l4 * 4]);

    // ---- attnout (bf16) -> R2, b64 writes ----
    #pragma unroll
    for (int nt = 0; nt < 2; ++nt)
        #pragma unroll
        for (int qt = 0; qt < 4; ++qt) {
            int q = qt * 16 + l15;
            int f0 = (h * 32 + nt * 16 + l4 * 4) ^ sw15;  // q&7 == l15&7
            union { u32 u[2]; s16x4 s; } pk;
            pk.u[0] = pk2(O[nt][qt][0], O[nt][qt][1]);
            pk.u[1] = pk2(O[nt][qt][2], O[nt][qt][3]);
            *reinterpret_cast<s16x4*>(&lds[8192 + q * 128 + f0]) = pk.s;
        }
    __syncthreads();  // B3: attnout published

    // ---- stage 5: out = attnout @ Wo + bo (SWAPPED -> float4 stores) ----
    {
        float* outw = out + (size_t)win * 8192;
        #pragma unroll
        for (int mt = 0; mt < 4; ++mt) {
            bf16x8 af[4];
            #pragma unroll
            for (int ks = 0; ks < 4; ++ks)
                af[ks] = *reinterpret_cast<const bf16x8*>(
                    &lds[8192 + (mt * 16 + l15) * 128 + ((ks * 32 + l4 * 8) ^ sw15)]);
            __builtin_amdgcn_s_setprio(1);
            #pragma unroll
            for (int nt = 0; nt < 2; ++nt) {
                f32x4 a = zero;
                #pragma unroll
                for (int ks = 0; ks < 4; ++ks) a = MFMA16(wf[nt][ks], af[ks], a);
                float4 st;
                st.x = a[0] + bo4[nt].x;
                st.y = a[1] + bo4[nt].y;
                st.z = a[2] + bo4[nt].z;
                st.w = a[3] + bo4[nt].w;
                *reinterpret_cast<float4*>(
                    &outw[(size_t)(mt * 16 + l15) * 128 + h * 32 + nt * 16 + l4 * 4]) = st;
            }
            __builtin_amdgcn_s_setprio(0);
        }
    }
}

extern "C" void kernel_launch(void* const* d_in, const int* in_sizes, int n_in,
                              void* d_out, int out_size, void* d_ws, size_t ws_size,
                              hipStream_t stream) {
    const float* patches  = (const float*)d_in[0];
    const float* Wq       = (const float*)d_in[1];
    const float* bq       = (const float*)d_in[2];
    const float* Wk       = (const float*)d_in[3];
    const float* bk       = (const float*)d_in[4];
    const float* Wv       = (const float*)d_in[5];
    const float* bv       = (const float*)d_in[6];
    const float* pos_bias = (const float*)d_in[7];
    const float* Wo       = (const float*)d_in[8];
    const float* bo       = (const float*)d_in[9];
    // d_in[10] (mask) is recomputed analytically in prep_kernel.

    char* ws = (char*)d_ws;
    unsigned short* WT  = (unsigned short*)(ws);            // 98304 B
    unsigned short* WoT = (unsigned short*)(ws + 98304);    // 32768 B
    float* bqkv         = (float*)(ws + 131072);            // 1536 B
    float* bm           = (float*)(ws + 132608);            // 65536 B (16B-aligned)

    hipLaunchKernelGGL(prep_kernel, dim3(64), dim3(256), 0, stream,
                       Wq, bq, Wk, bk, Wv, bv, pos_bias, Wo, WT, WoT, bqkv, bm);
    hipLaunchKernelGGL(swin_kernel, dim3(4096), dim3(256), 0, stream,
                       patches, WT, bqkv, bm, WoT, bo, (float*)d_out);
}

// Round 5
// 108.487 us; speedup vs baseline: 2.1465x; 1.2292x over previous
//
#include <hip/hip_runtime.h>
#include <hip/hip_bf16.h>

typedef float f32x4 __attribute__((ext_vector_type(4)));
typedef short bf16x8 __attribute__((ext_vector_type(8)));
typedef short s16x4 __attribute__((ext_vector_type(4)));
typedef unsigned int u32;

#define MFMA16(a, b, c) __builtin_amdgcn_mfma_f32_16x16x32_bf16((a), (b), (c), 0, 0, 0)

// pack two floats -> u32 of 2 bf16 (RNE, v_cvt_pk_bf16_f32)
__device__ __forceinline__ u32 pk2(float lo, float hi) {
    union { __hip_bfloat162 h; u32 u; } c;
    c.h = __float22bfloat162_rn(float2{lo, hi});
    return c.u;
}

// round-to-nearest-even float -> bf16 bits (helper for prep)
__device__ __forceinline__ unsigned short f2bf(float x) {
    union { float f; unsigned int u; } a; a.f = x;
    unsigned int r = a.u + 0x7fffu + ((a.u >> 16) & 1u);
    return (unsigned short)(r >> 16);
}

// ---------------------------------------------------------------------------
// prep: pack bf16 transposed weights + pre-gathered bias/mask tables into ws
//   WT  [c=384][kk=128] bf16, c = h*96 + p*32 + n   (p: 0=q,1=k,2=v)
//   WoT [f=128][e=128]  bf16  (WoT[f][e] = Wo[e][f])
//   bqkv[384] f32 (same c indexing)
//   bm  [v=4][qt=4][kt=4][lane=64][r=4] f32: (bias*log2e, -1e30 if masked)
//     for q = qt*16 + (lane&15), k = kt*16 + (lane>>4)*4 + r   (swapped layout)
// ---------------------------------------------------------------------------
__global__ void prep_kernel(const float* __restrict__ Wq, const float* __restrict__ bq,
                            const float* __restrict__ Wk, const float* __restrict__ bk,
                            const float* __restrict__ Wv, const float* __restrict__ bv,
                            const float* __restrict__ pos_bias, const float* __restrict__ Wo,
                            unsigned short* __restrict__ WT, unsigned short* __restrict__ WoT,
                            float* __restrict__ bqkv, float* __restrict__ bm) {
    const float LOG2E = 1.4426950408889634f;
    int t = blockIdx.x * blockDim.x + threadIdx.x;
    int nt = gridDim.x * blockDim.x;
    for (int i = t; i < 384 * 128; i += nt) {
        int c = i >> 7, kk = i & 127;
        int h = c / 96, rem = c - h * 96, p = rem >> 5, n = rem & 31;
        const float* W = (p == 0) ? Wq : (p == 1 ? Wk : Wv);
        WT[i] = f2bf(W[(h * 128 + kk) * 32 + n]);
    }
    for (int i = t; i < 128 * 128; i += nt) {
        int n = i >> 7, kk = i & 127;
        WoT[i] = f2bf(Wo[kk * 128 + n]);
    }
    for (int i = t; i < 384; i += nt) {
        int h = i / 96, rem = i - h * 96, p = rem >> 5, n = rem & 31;
        const float* b = (p == 0) ? bq : (p == 1 ? bk : bv);
        bqkv[i] = b[h * 32 + n];
    }
    for (int i = t; i < 4 * 4 * 4 * 64 * 4; i += nt) {
        int r = i & 3, l = (i >> 2) & 63, kt = (i >> 8) & 3, qt = (i >> 10) & 3, v = (i >> 12) & 3;
        int q = qt * 16 + (l & 15);
        int k = kt * 16 + ((l >> 4) << 2) + r;
        int qi = q >> 3, qj = q & 7, ki = k >> 3, kj = k & 7;
        bool masked = (((v >> 1) != 0) && ((qi < 4) != (ki < 4))) ||
                      (((v & 1) != 0) && ((qj < 4) != (kj < 4)));
        bm[i] = masked ? -1e30f : pos_bias[(qi - ki + 7) * 15 + (qj - kj + 7)] * LOG2E;
    }
}

// ---------------------------------------------------------------------------
// fused Swin window attention v5: one block (4 waves) per window, wave = head.
// v4 structure (Q/K in-register via shfl-exchange, 32 KB LDS, 3 barriers)
// with locality fixes:
//   - __launch_bounds__(256,3): 4 blocks/CU thrashed L2 (WRITE_SIZE 131->221MB
//     in R4); 3/CU keeps the chip-wide streaming working set within the 32 MB
//     aggregate L2 so output lines are written to HBM exactly once.
//   - XCD-aware window swizzle: dispatch round-robins blocks over 8 XCDs, so
//     win = (bid%8)*512 + bid/8 gives each XCD a contiguous 512-window range
//     -> contiguous 16 MB read/write streams per per-XCD L2.
// LDS (32 KB, shorts):
//   R1 [0,8192)      : xb[64][128]  -> V^T[4 heads][32][64] overlay (after B2)
//   R2 [8192,16384)  : attnout[64][128]
// ---------------------------------------------------------------------------
__launch_bounds__(256, 3)
__global__ void swin_kernel(const float* __restrict__ patches,
                            const unsigned short* __restrict__ WT,
                            const float* __restrict__ bqkv,
                            const float* __restrict__ bm,
                            const unsigned short* __restrict__ WoT,
                            const float* __restrict__ bo,
                            float* __restrict__ out) {
    __shared__ short lds[16384];
    const int win = ((blockIdx.x & 7) << 9) | (blockIdx.x >> 3);  // XCD swizzle
    const int tid = threadIdx.x;
    const int lane = tid & 63;
    const int h = tid >> 6;
    const int l15 = lane & 15, l4 = lane >> 4;
    const int sw15 = (l15 & 7) << 3;       // swizzle for rows congruent to l15 (mod 8)
    const f32x4 zero = {0.f, 0.f, 0.f, 0.f};
    const int sA = ((l4 & 1) << 5) + l15;  // exchange src lane, words 0,1
    const int sB = sA + 16;                //                    words 2,3
    const float rs2 = 0.2550348660629988f; // log2(e)/sqrt(32)
    const float4* bmv = reinterpret_cast<const float4*>(bm);

    // ---- stage 1: patches (f32) -> xb (bf16, swizzled) ----
    {
        const float4* src = reinterpret_cast<const float4*>(patches + (size_t)win * 8192);
        #pragma unroll
        for (int i = 0; i < 8; ++i) {
            int idx4 = i * 256 + tid;
            float4 v = src[idx4];
            int row = idx4 >> 5, col = (idx4 & 31) << 2;
            union { u32 u[2]; s16x4 s; } pk;
            pk.u[0] = pk2(v.x, v.y);
            pk.u[1] = pk2(v.z, v.w);
            *reinterpret_cast<s16x4*>(&lds[row * 128 + (col ^ ((row & 7) << 3))]) = pk.s;
        }
    }
    __syncthreads();  // B1: xb ready

    // ---- stage 2a: x fragments (all waves read all of xb) ----
    bf16x8 xa[4][4];
    #pragma unroll
    for (int mt = 0; mt < 4; ++mt)
        #pragma unroll
        for (int ks = 0; ks < 4; ++ks)
            xa[mt][ks] = *reinterpret_cast<const bf16x8*>(
                &lds[(mt * 16 + l15) * 128 + ((ks * 32 + l4 * 8) ^ sw15)]);
    __syncthreads();  // B2: xa reads done -> V^T may overlay xb

    // ---- stage 2b: Q,K projection (SWAPPED mfma(W,X)); C-out -> shfl-exchange
    //      directly into QK^T fragments (no LDS). ct 0,1 = Q; ct 2,3 = K. ----
    bf16x8 qf[4], kf[4];
    #pragma unroll
    for (int ct = 0; ct < 4; ++ct) {
        bf16x8 wb[4];
        #pragma unroll
        for (int ks = 0; ks < 4; ++ks)
            wb[ks] = *reinterpret_cast<const bf16x8*>(
                &WT[(h * 96 + ct * 16 + l15) * 128 + ks * 32 + l4 * 8]);
        float b4[4];
        #pragma unroll
        for (int r = 0; r < 4; ++r) b4[r] = bqkv[h * 96 + ct * 16 + l4 * 4 + r];
        #pragma unroll
        for (int mt = 0; mt < 4; ++mt) {
            f32x4 a = zero;
            __builtin_amdgcn_s_setprio(1);
            #pragma unroll
            for (int ks = 0; ks < 4; ++ks) a = MFMA16(wb[ks], xa[mt][ks], a);
            __builtin_amdgcn_s_setprio(0);
            u32 pw0 = pk2(a[0] + b4[0], a[1] + b4[1]);
            u32 pw1 = pk2(a[2] + b4[2], a[3] + b4[3]);
            u32 e0 = __shfl(pw0, sA);
            u32 e1 = __shfl(pw1, sA);
            u32 e2 = __shfl(pw0, sB);
            u32 e3 = __shfl(pw1, sB);
            if ((ct & 1) == (l4 >> 1)) {  // this lane's fragment comes from this ct
                union { u32 u[4]; bf16x8 v; } c;
                c.u[0] = e0; c.u[1] = e1; c.u[2] = e2; c.u[3] = e3;
                if (ct < 2) qf[mt] = c.v; else kf[mt] = c.v;
            }
        }
    }

    // ---- stage 2c: V projection (normal mfma(X,W)) -> V^T in R1, b64 writes
    #pragma unroll
    for (int ctv = 0; ctv < 2; ++ctv) {
        bf16x8 wb[4];
        #pragma unroll
        for (int ks = 0; ks < 4; ++ks)
            wb[ks] = *reinterpret_cast<const bf16x8*>(
                &WT[(h * 96 + 64 + ctv * 16 + l15) * 128 + ks * 32 + l4 * 8]);
        float bb = bqkv[h * 96 + 64 + ctv * 16 + l15];
        __builtin_amdgcn_s_setprio(1);
        #pragma unroll
        for (int mt = 0; mt < 4; ++mt) {
            f32x4 a = zero;
            #pragma unroll
            for (int ks = 0; ks < 4; ++ks) a = MFMA16(xa[mt][ks], wb[ks], a);
            int n = ctv * 16 + l15;
            int tok0 = (mt * 16 + l4 * 4) ^ sw15;  // n&7 == l15&7
            union { u32 u[2]; s16x4 s; } pk;
            pk.u[0] = pk2(a[0] + bb, a[1] + bb);
            pk.u[1] = pk2(a[2] + bb, a[3] + bb);
            *reinterpret_cast<s16x4*>(&lds[h * 2048 + n * 64 + tok0]) = pk.s;
        }
        __builtin_amdgcn_s_setprio(0);
    }

    // ---- stage 3+4 (wave-local, barrier-free): swapped QK^T, in-reg softmax,
    //      shfl-built P fragments, swapped PV ----
    bf16x8 vf[2][2];
    #pragma unroll
    for (int nt = 0; nt < 2; ++nt)
        #pragma unroll
        for (int ks = 0; ks < 2; ++ks)
            vf[nt][ks] = *reinterpret_cast<const bf16x8*>(
                &lds[h * 2048 + (nt * 16 + l15) * 64 + ((ks * 32 + l4 * 8) ^ sw15)]);

    f32x4 O[2][4];  // [nt][qt], O^T layout: row n, col q
    #pragma unroll
    for (int nt = 0; nt < 2; ++nt)
        #pragma unroll
        for (int qt = 0; qt < 4; ++qt) O[nt][qt] = zero;

    const int mv = (((win >> 4) & 15) == 15 ? 2 : 0) + ((win & 15) == 15 ? 1 : 0);

    float4 bcur[4], bnxt[4];
    #pragma unroll
    for (int kt = 0; kt < 4; ++kt) bcur[kt] = bmv[((mv * 4 + 0) * 4 + kt) * 64 + lane];

    #pragma unroll
    for (int qt = 0; qt < 4; ++qt) {
        f32x4 LT[4];
        __builtin_amdgcn_s_setprio(1);
        #pragma unroll
        for (int kt = 0; kt < 4; ++kt) LT[kt] = MFMA16(kf[kt], qf[qt], zero);
        __builtin_amdgcn_s_setprio(0);

        if (qt < 3) {  // prefetch next qt's bias/mask under this qt's softmax
            #pragma unroll
            for (int kt = 0; kt < 4; ++kt)
                bnxt[kt] = bmv[((mv * 4 + qt + 1) * 4 + kt) * 64 + lane];
        }

        // lane holds S[q=qt*16+l15][k=kt*16+l4*4+r]
        float x[4][4];
        float m = -3.0e38f;
        #pragma unroll
        for (int kt = 0; kt < 4; ++kt) {
            x[kt][0] = LT[kt][0] * rs2 + bcur[kt].x;
            x[kt][1] = LT[kt][1] * rs2 + bcur[kt].y;
            x[kt][2] = LT[kt][2] * rs2 + bcur[kt].z;
            x[kt][3] = LT[kt][3] * rs2 + bcur[kt].w;
            m = fmaxf(m, fmaxf(fmaxf(x[kt][0], x[kt][1]), fmaxf(x[kt][2], x[kt][3])));
        }
        m = fmaxf(m, __shfl_xor(m, 16));
        m = fmaxf(m, __shfl_xor(m, 32));
        float s = 0.f;
        #pragma unroll
        for (int kt = 0; kt < 4; ++kt)
            #pragma unroll
            for (int r = 0; r < 4; ++r) {
                float e = exp2f(x[kt][r] - m);
                x[kt][r] = e;
                s += e;
            }
        s += __shfl_xor(s, 16);
        s += __shfl_xor(s, 32);
        float inv = 1.0f / s;

        u32 wp[4][2];
        #pragma unroll
        for (int kt = 0; kt < 4; ++kt) {
            wp[kt][0] = pk2(x[kt][0] * inv, x[kt][1] * inv);
            wp[kt][1] = pk2(x[kt][2] * inv, x[kt][3] * inv);
        }
        // exchange -> B-frag of PV: lane needs P[q=l15][k=ks*32+l4*8+j]
        u32 fr[2][4];
        #pragma unroll
        for (int kt = 0; kt < 4; ++kt) {
            u32 a0 = __shfl(wp[kt][0], sA);
            u32 a1 = __shfl(wp[kt][1], sA);
            u32 b0 = __shfl(wp[kt][0], sB);
            u32 b1 = __shfl(wp[kt][1], sB);
            if ((kt & 1) == (l4 >> 1)) {
                const int ks = kt >> 1;
                fr[ks][0] = a0; fr[ks][1] = a1; fr[ks][2] = b0; fr[ks][3] = b1;
            }
        }
        bf16x8 pf0, pf1;
        {
            union { u32 u[4]; bf16x8 v; } c0, c1;
            c0.u[0] = fr[0][0]; c0.u[1] = fr[0][1]; c0.u[2] = fr[0][2]; c0.u[3] = fr[0][3];
            c1.u[0] = fr[1][0]; c1.u[1] = fr[1][1]; c1.u[2] = fr[1][2]; c1.u[3] = fr[1][3];
            pf0 = c0.v; pf1 = c1.v;
        }
        __builtin_amdgcn_s_setprio(1);
        #pragma unroll
        for (int nt = 0; nt < 2; ++nt) {
            O[nt][qt] = MFMA16(vf[nt][0], pf0, O[nt][qt]);
            O[nt][qt] = MFMA16(vf[nt][1], pf1, O[nt][qt]);
        }
        __builtin_amdgcn_s_setprio(0);

        if (qt < 3) {
            #pragma unroll
            for (int kt = 0; kt < 4; ++kt) bcur[kt] = bnxt[kt];
        }
    }

    // ---- stage 5 weight loads issued early (hide under attnout + barrier) ----
    bf16x8 wf[2][4];
    #pragma unroll
    for (int nt = 0; nt < 2; ++nt)
        #pragma unroll
        for (int ks = 0; ks < 4; ++ks)
            wf[nt][ks] = *reinterpret_cast<const bf16x8*>(
                &WoT[(h * 32 + nt * 16 + l15) * 128 + ks * 32 + l4 * 8]);
    float4 bo4[2];
    #pragma unroll
    for (int nt = 0; nt < 2; ++nt)
        bo4[nt] = *reinterpret_cast<const float4*>(&bo[h * 32 + nt * 16 + l4 * 4]);

    // ---- attnout (bf16) -> R2, b64 writes ----
    #pragma unroll
    for (int nt = 0; nt < 2; ++nt)
        #pragma unroll
        for (int qt = 0; qt < 4; ++qt) {
            int q = qt * 16 + l15;
            int f0 = (h * 32 + nt * 16 + l4 * 4) ^ sw15;  // q&7 == l15&7
            union { u32 u[2]; s16x4 s; } pk;
            pk.u[0] = pk2(O[nt][qt][0], O[nt][qt][1]);
            pk.u[1] = pk2(O[nt][qt][2], O[nt][qt][3]);
            *reinterpret_cast<s16x4*>(&lds[8192 + q * 128 + f0]) = pk.s;
        }
    __syncthreads();  // B3: attnout published

    // ---- stage 5: out = attnout @ Wo + bo (SWAPPED -> float4 stores) ----
    {
        float* outw = out + (size_t)win * 8192;
        #pragma unroll
        for (int mt = 0; mt < 4; ++mt) {
            bf16x8 af[4];
            #pragma unroll
            for (int ks = 0; ks < 4; ++ks)
                af[ks] = *reinterpret_cast<const bf16x8*>(
                    &lds[8192 + (mt * 16 + l15) * 128 + ((ks * 32 + l4 * 8) ^ sw15)]);
            __builtin_amdgcn_s_setprio(1);
            #pragma unroll
            for (int nt = 0; nt < 2; ++nt) {
                f32x4 a = zero;
                #pragma unroll
                for (int ks = 0; ks < 4; ++ks) a = MFMA16(wf[nt][ks], af[ks], a);
                float4 st;
                st.x = a[0] + bo4[nt].x;
                st.y = a[1] + bo4[nt].y;
                st.z = a[2] + bo4[nt].z;
                st.w = a[3] + bo4[nt].w;
                *reinterpret_cast<float4*>(
                    &outw[(size_t)(mt * 16 + l15) * 128 + h * 32 + nt * 16 + l4 * 4]) = st;
            }
            __builtin_amdgcn_s_setprio(0);
        }
    }
}

extern "C" void kernel_launch(void* const* d_in, const int* in_sizes, int n_in,
                              void* d_out, int out_size, void* d_ws, size_t ws_size,
                              hipStream_t stream) {
    const float* patches  = (const float*)d_in[0];
    const float* Wq       = (const float*)d_in[1];
    const float* bq       = (const float*)d_in[2];
    const float* Wk       = (const float*)d_in[3];
    const float* bk       = (const float*)d_in[4];
    const float* Wv       = (const float*)d_in[5];
    const float* bv       = (const float*)d_in[6];
    const float* pos_bias = (const float*)d_in[7];
    const float* Wo       = (const float*)d_in[8];
    const float* bo       = (const float*)d_in[9];
    // d_in[10] (mask) is recomputed analytically in prep_kernel.

    char* ws = (char*)d_ws;
    unsigned short* WT  = (unsigned short*)(ws);            // 98304 B
    unsigned short* WoT = (unsigned short*)(ws + 98304);    // 32768 B
    float* bqkv         = (float*)(ws + 131072);            // 1536 B
    float* bm           = (float*)(ws + 132608);            // 65536 B (16B-aligned)

    hipLaunchKernelGGL(prep_kernel, dim3(64), dim3(256), 0, stream,
                       Wq, bq, Wk, bk, Wv, bv, pos_bias, Wo, WT, WoT, bqkv, bm);
    hipLaunchKernelGGL(swin_kernel, dim3(4096), dim3(256), 0, stream,
                       patches, WT, bqkv, bm, WoT, bo, (float*)d_out);
}